// Round 1
// baseline (127.818 us; speedup 1.0000x reference)
//
#include <hip/hip_runtime.h>

// GAT forward: B=8, N=1024, IN_F=OUT_F=128, H=4, HD=32, LeakyReLU(0.2), softmax over j.
// Decomposition:
//   K1 (proj): h = x@W (fp32), plus s[b,h,n]=<h,a_src>, d[b,h,n]=<h,a_dst>
//   K2 (attn): w_ij = exp(LeakyReLU(s_i+d_j)) = (s_i+d_j>=0) ? e^{s_i}e^{d_j} : e^{.2 s_i}e^{.2 d_j}
//              -> no exp in inner loop; acc[i,:] += w*h[j,:], l[i] += w.  j split in NJ chunks.
//   K3 (combine): out = sum_jc acc / sum_jc l, written in (b,i,h,dd) layout.

constexpr int CB  = 8;
constexpr int CN  = 1024;
constexpr int CF  = 128;
constexpr int CH  = 4;
constexpr int CHD = 32;
constexpr int CBH = CB * CH;        // 32
constexpr int CROWS = CB * CN;      // 8192
constexpr int CBHN = CBH * CN;      // 32768

// ---------------- Kernel 1: projection + attention dots ----------------
// grid 1024 blocks x 128 threads, 8 rows per block.
__global__ __launch_bounds__(128) void proj_kernel(
    const float* __restrict__ x, const float* __restrict__ W,
    const float* __restrict__ a_src, const float* __restrict__ a_dst,
    float* __restrict__ h_ws, float* __restrict__ s_ws, float* __restrict__ d_ws)
{
    __shared__ float4 xs4[8 * 32];   // 8 rows x 128 floats = 4KB (reused as hs later)
    const int tid  = threadIdx.x;
    const int row0 = blockIdx.x * 8;
    const float4* x4 = (const float4*)x;
    for (int idx = tid; idx < 256; idx += 128) xs4[idx] = x4[row0 * 32 + idx];
    __syncthreads();

    float acc[8] = {0.f,0.f,0.f,0.f,0.f,0.f,0.f,0.f};
    const int col = tid;
    for (int k4 = 0; k4 < 32; ++k4) {
        const float w0 = W[(k4 * 4 + 0) * CF + col];
        const float w1 = W[(k4 * 4 + 1) * CF + col];
        const float w2 = W[(k4 * 4 + 2) * CF + col];
        const float w3 = W[(k4 * 4 + 3) * CF + col];
        #pragma unroll
        for (int r = 0; r < 8; ++r) {
            const float4 xv = xs4[r * 32 + k4];
            acc[r] += xv.x * w0 + xv.y * w1 + xv.z * w2 + xv.w * w3;
        }
    }
    // write h in [bh][n][dd] layout for coalesced per-(b,h) access in K2
    const int head = col >> 5, dd = col & 31;
    #pragma unroll
    for (int r = 0; r < 8; ++r) {
        const int row = row0 + r, b = row >> 10, n = row & 1023;
        h_ws[(size_t)((b * CH + head) * CN + n) * CHD + dd] = acc[r];
    }
    __syncthreads();                   // everyone done reading xs4
    float* hs = (float*)xs4;           // reuse as [8][128]
    #pragma unroll
    for (int r = 0; r < 8; ++r) hs[r * CF + col] = acc[r];
    __syncthreads();
    if (tid < 64) {
        const int r = tid >> 3, q = tid & 7, hh = q & 3, which = q >> 2;
        const float* av = (which ? a_dst : a_src) + hh * CHD;
        float sacc = 0.f;
        // rotated start to avoid 32-way LDS bank conflicts
        for (int k = 0; k < 32; ++k) {
            const int kk = (k + tid) & 31;
            sacc += hs[r * CF + hh * 32 + kk] * av[kk];
        }
        const int row = row0 + r, b = row >> 10, n = row & 1023;
        (which ? d_ws : s_ws)[(b * CH + hh) * CN + n] = sacc;
    }
}

// ---------------- Kernel 2: attention partial sums ----------------
// grid = CBH * 4 * NJ blocks x 256 threads.
// Block handles (bh, it, jc): 256 rows i = it*256 + ii*64 + islot (ii<4, islot<64),
// j in [jc*JT, jc*JT+JT) staged 128 at a time. Thread = (islot, part): 4 rows x 8 dims.
__global__ __launch_bounds__(256) void attn_kernel(
    const float4* __restrict__ h4, const float* __restrict__ s_ws,
    const float* __restrict__ d_ws, float* __restrict__ pacc,
    float* __restrict__ pl, float* __restrict__ out, int NJ, int direct)
{
    __shared__ float4 hjs4[128 * 8];   // 16KB: 128 j-rows x 32 floats
    __shared__ float  djs[128];
    __shared__ float  Aj[128];         // exp(d_j)
    __shared__ float  Bj[128];         // exp(0.2*d_j)

    int idx = blockIdx.x;
    const int jc = idx % NJ; idx /= NJ;
    const int it = idx & 3;  const int bh = idx >> 2;
    const int base = bh * CN;
    const int JT = CN / NJ;
    const int tid = threadIdx.x;
    const int part = tid & 3, islot = tid >> 2, dd0 = part * 8;

    float sreg[4], c1[4], c2[4];
    #pragma unroll
    for (int ii = 0; ii < 4; ++ii) {
        const float s = s_ws[base + it * 256 + ii * 64 + islot];
        sreg[ii] = s; c1[ii] = __expf(s); c2[ii] = __expf(0.2f * s);
    }
    float acc[4][8];
    #pragma unroll
    for (int ii = 0; ii < 4; ++ii)
        #pragma unroll
        for (int q = 0; q < 8; ++q) acc[ii][q] = 0.f;
    float lacc[4] = {0.f, 0.f, 0.f, 0.f};

    for (int jt = jc * JT; jt < jc * JT + JT; jt += 128) {
        __syncthreads();
        for (int q = tid; q < 1024; q += 256) hjs4[q] = h4[(size_t)(base + jt) * 8 + q];
        if (tid < 128) {
            const float dj = d_ws[base + jt + tid];
            djs[tid] = dj; Aj[tid] = __expf(dj); Bj[tid] = __expf(0.2f * dj);
        }
        __syncthreads();
        for (int j = 0; j < 128; ++j) {
            const float dj = djs[j], A = Aj[j], Bv = Bj[j];
            const float4 hv0 = hjs4[j * 8 + part * 2];
            const float4 hv1 = hjs4[j * 8 + part * 2 + 1];
            #pragma unroll
            for (int ii = 0; ii < 4; ++ii) {
                const bool pos = (sreg[ii] + dj) >= 0.f;
                const float w = pos ? c1[ii] * A : c2[ii] * Bv;
                lacc[ii] += w;
                acc[ii][0] += w * hv0.x; acc[ii][1] += w * hv0.y;
                acc[ii][2] += w * hv0.z; acc[ii][3] += w * hv0.w;
                acc[ii][4] += w * hv1.x; acc[ii][5] += w * hv1.y;
                acc[ii][6] += w * hv1.z; acc[ii][7] += w * hv1.w;
            }
        }
    }

    #pragma unroll
    for (int ii = 0; ii < 4; ++ii) {
        const int irow = base + it * 256 + ii * 64 + islot;
        if (direct) {
            const int b = irow >> 12, rem = irow & 4095, hh = rem >> 10, i = rem & 1023;
            const float inv = 1.0f / lacc[ii];
            float* o = out + (size_t)(b * CN + i) * CF + hh * 32 + dd0;
            float4 v0 = {acc[ii][0]*inv, acc[ii][1]*inv, acc[ii][2]*inv, acc[ii][3]*inv};
            float4 v1 = {acc[ii][4]*inv, acc[ii][5]*inv, acc[ii][6]*inv, acc[ii][7]*inv};
            ((float4*)o)[0] = v0; ((float4*)o)[1] = v1;
        } else {
            float* pa = pacc + ((size_t)jc * CBHN + irow) * 32 + dd0;
            float4 v0 = {acc[ii][0], acc[ii][1], acc[ii][2], acc[ii][3]};
            float4 v1 = {acc[ii][4], acc[ii][5], acc[ii][6], acc[ii][7]};
            ((float4*)pa)[0] = v0; ((float4*)pa)[1] = v1;
            if (part == 0) pl[(size_t)jc * CBHN + irow] = lacc[ii];
        }
    }
}

// ---------------- Kernel 3: combine j-chunks, divide, write out ----------------
__global__ __launch_bounds__(256) void combine_kernel(
    const float* __restrict__ pacc, const float* __restrict__ pl,
    float* __restrict__ out, int NJ)
{
    const int idx = blockIdx.x * 256 + threadIdx.x;   // < CBHN*32
    const int row = idx >> 5, dd = idx & 31;
    float a = 0.f, l = 0.f;
    for (int jc = 0; jc < NJ; ++jc) {
        a += pacc[((size_t)jc * CBHN + row) * 32 + dd];
        l += pl[(size_t)jc * CBHN + row];
    }
    const int b = row >> 12, rem = row & 4095, hh = rem >> 10, i = rem & 1023;
    out[(size_t)(b * CN + i) * CF + hh * 32 + dd] = a / l;
}

extern "C" void kernel_launch(void* const* d_in, const int* in_sizes, int n_in,
                              void* d_out, int out_size, void* d_ws, size_t ws_size,
                              hipStream_t stream) {
    const float* x     = (const float*)d_in[0];
    const float* W     = (const float*)d_in[1];
    const float* a_src = (const float*)d_in[2];
    const float* a_dst = (const float*)d_in[3];
    float* out = (float*)d_out;

    char* ws = (char*)d_ws;
    size_t off = 0;
    float* h_ws = (float*)(ws + off); off += (size_t)CROWS * CF * 4;        // 4 MB
    float* s_ws = (float*)(ws + off); off += (size_t)CBHN * 4;              // 128 KB
    float* dws  = (float*)(ws + off); off += (size_t)CBHN * 4;              // 128 KB

    int NJ = 4;
    size_t need_pacc = (size_t)NJ * CBHN * 32 * 4;   // 16 MB
    size_t need_pl   = (size_t)NJ * CBHN * 4;        // 512 KB
    float* pacc = (float*)(ws + off);
    float* pl   = (float*)(ws + off + need_pacc);
    if (off + need_pacc + need_pl > ws_size) { NJ = 1; pacc = h_ws; pl = h_ws; }

    proj_kernel<<<CROWS / 8, 128, 0, stream>>>(x, W, a_src, a_dst, h_ws, s_ws, dws);

    const int direct = (NJ == 1) ? 1 : 0;
    attn_kernel<<<CBH * 4 * NJ, 256, 0, stream>>>(
        (const float4*)h_ws, s_ws, dws, pacc, pl, out, NJ, direct);

    if (!direct) {
        combine_kernel<<<(CBHN * 32) / 256, 256, 0, stream>>>(pacc, pl, out, NJ);
    }
}